// Round 2
// baseline (159.263 us; speedup 1.0000x reference)
//
#include <hip/hip_runtime.h>
#include <math.h>

#define HW       512
#define NPT      512
#define BATCHN   4
#define RMAX_CAP 37
#define CFACTOR  2.0f
#define TILE     32
#define TPD      (HW / TILE)      // 16 tiles per dim
#define NTILE    (TPD * TPD)      // 256 tiles per batch
#define CAP      512              // max entries per tile (== NPT, can't overflow)

// ws layout:
//   off 0    : float r[BATCHN]
//   off 16   : int   rm
//   off 64   : int   counts[BATCHN*NTILE]          (4 KiB)
//   off 8192 : int   entries[BATCHN*NTILE*CAP]     (2 MiB)

__global__ __launch_bounds__(NPT) void maxmin_kernel(const float* __restrict__ loc,
                                                     float* __restrict__ ws_r) {
    __shared__ float2 pts[NPT];
    __shared__ float red[NPT / 64];
    const int b = blockIdx.x;
    const int t = threadIdx.x;
    const float2* L = (const float2*)(loc + (size_t)b * NPT * 2);
    pts[t] = L[t];
    __syncthreads();
    const float2 p = pts[t];
    float mind = 1e30f;
#pragma unroll 4
    for (int j = 0; j < NPT; ++j) {
        float dx = p.x - pts[j].x;
        float dy = p.y - pts[j].y;
        float d2 = dx * dx + dy * dy;
        if (j != t) mind = fminf(mind, d2);
    }
    float m = mind;
#pragma unroll
    for (int off = 1; off < 64; off <<= 1)
        m = fmaxf(m, __shfl_xor(m, off, 64));
    const int wid = t >> 6, lane = t & 63;
    if (lane == 0) red[wid] = m;
    __syncthreads();
    if (t == 0) {
        float mm = red[0];
#pragma unroll
        for (int w = 1; w < NPT / 64; ++w) mm = fmaxf(mm, red[w]);
        ws_r[b] = sqrtf(mm) * CFACTOR;   // r[b] = (maxmin NN dist) * C_FACTOR
    }
}

__global__ void finalize_kernel(const float* __restrict__ ws_r, int* __restrict__ ws_rm) {
    float m = ws_r[0];
#pragma unroll
    for (int b = 1; b < BATCHN; ++b) m = fmaxf(m, ws_r[b]);
    *ws_rm = (int)fminf(ceilf(m), (float)RMAX_CAP);   // r_max = int(min(ceil(max r), 37))
}

// One thread per point: append point index to every tile its (conservative)
// window bounding box touches. <=16 tiles/point, ~25K atomics total.
__global__ __launch_bounds__(NPT) void bin_kernel(const float* __restrict__ loc,
                                                  const int* __restrict__ ws_rm,
                                                  int* __restrict__ counts,
                                                  int* __restrict__ entries) {
    const int b = blockIdx.x;
    const int n = threadIdx.x;
    const int rm = *ws_rm;
    const float lo = (float)rm, hi = (float)(HW - rm);
    const float x = loc[((size_t)b * NPT + n) * 2 + 0];
    const float y = loc[((size_t)b * NPT + n) * 2 + 1];
    const float tx = fminf(fmaxf(x, lo), hi);
    const float ty = fminf(fmaxf(y, lo), hi);
    const int itx = (int)floorf(tx), ity = (int)floorf(ty);
    const int x0 = max(itx - rm - 1, 0), x1 = min(itx + rm + 1, HW - 1);
    const int y0 = max(ity - rm - 1, 0), y1 = min(ity + rm + 1, HW - 1);
    const int tx0 = x0 / TILE, tx1 = x1 / TILE;
    const int ty0 = y0 / TILE, ty1 = y1 / TILE;
    for (int tyi = ty0; tyi <= ty1; ++tyi)
        for (int txi = tx0; txi <= tx1; ++txi) {
            const int tid = b * NTILE + tyi * TPD + txi;
            const int slot = atomicAdd(&counts[tid], 1);
            entries[(size_t)tid * CAP + slot] = n;
        }
}

// One block per (tile, batch). Registers accumulate 4 px/thread, plain stores.
// Faithful multiplicity: pixel ix receives point's window entry fdx iff
// floorf(fp32(fdx + tx)) == ix, fdx in [-rm, rm). Only fdx in
// {ix-floor(tx)-1, ix-floor(tx), +1} can match (fp32 round-to-nearest can
// raise floor by at most 1); count matches and scale by mult_x*mult_y.
__global__ __launch_bounds__(256) void gather_kernel(const float* __restrict__ loc,
                                                     const float* __restrict__ alpha,
                                                     const float* __restrict__ ws_r,
                                                     const int* __restrict__ ws_rm,
                                                     const int* __restrict__ counts,
                                                     const int* __restrict__ entries,
                                                     float* __restrict__ out) {
    __shared__ float sx[CAP], sy[CAP], stx[CAP], sty[CAP], sa0[CAP], sa1[CAP];
    const int tile = blockIdx.x;
    const int b = blockIdx.y;
    const int rm = *ws_rm;
    const float lo = (float)rm, hi = (float)(HW - rm);
    const float inv_r = 1.0f / ws_r[b];
    const int ox = (tile & (TPD - 1)) * TILE;
    const int oy = (tile >> 4) * TILE;
    const int count = counts[b * NTILE + tile];
    const int* ent = entries + (size_t)(b * NTILE + tile) * CAP;

    for (int j = threadIdx.x; j < count; j += 256) {
        const int n = ent[j];
        const float x = loc[((size_t)b * NPT + n) * 2 + 0];
        const float y = loc[((size_t)b * NPT + n) * 2 + 1];
        sx[j] = x;
        sy[j] = y;
        stx[j] = fminf(fmaxf(x, lo), hi);
        sty[j] = fminf(fmaxf(y, lo), hi);
        sa0[j] = alpha[((size_t)b * NPT + n) * 2 + 0];
        sa1[j] = alpha[((size_t)b * NPT + n) * 2 + 1];
    }
    __syncthreads();

    const int col = threadIdx.x & (TILE - 1);
    const int row0 = threadIdx.x >> 5;           // 0..7; rows row0 + 8k
    const int ix = ox + col;
    const float fix = (float)ix;
    float acc0[4] = {0.f, 0.f, 0.f, 0.f};
    float acc1[4] = {0.f, 0.f, 0.f, 0.f};

    for (int j = 0; j < count; ++j) {
        const float tx = stx[j];
        const int itx = (int)floorf(tx);
        const int bx = ix - itx;
        int mx = 0;
        { const int c = bx - 1; if (c >= -rm && c < rm && floorf((float)c + tx) == fix) ++mx; }
        { const int c = bx;     if (c >= -rm && c < rm && floorf((float)c + tx) == fix) ++mx; }
        { const int c = bx + 1; if (c >= -rm && c < rm && floorf((float)c + tx) == fix) ++mx; }
        if (mx == 0) continue;

        const float xx = sx[j];
        const float ddx = fix - xx;
        const float px2 = ddx * ddx;
        const float ty = sty[j];
        const float yy = sy[j];
        const int ity = (int)floorf(ty);
        const float a0 = sa0[j] * (float)mx;
        const float a1 = sa1[j] * (float)mx;

#pragma unroll
        for (int k = 0; k < 4; ++k) {
            const int iy = oy + row0 + 8 * k;
            const float fiy = (float)iy;
            const int by = iy - ity;
            int my = 0;
            { const int c = by - 1; if (c >= -rm && c < rm && floorf((float)c + ty) == fiy) ++my; }
            { const int c = by;     if (c >= -rm && c < rm && floorf((float)c + ty) == fiy) ++my; }
            { const int c = by + 1; if (c >= -rm && c < rm && floorf((float)c + ty) == fiy) ++my; }
            if (my == 0) continue;
            const float ddy = fiy - yy;
            const float dist = sqrtf(px2 + ddy * ddy) * inv_r;
            if (dist < 1.0f) {
                const float t1 = 1.0f - dist;
                const float t2 = t1 * t1;
                const float w = t2 * t2 * (4.0f * dist + 1.0f) * (float)my;
                acc0[k] += w * a0;
                acc1[k] += w * a1;
            }
        }
    }

    float* o0 = out + (size_t)b * 2 * HW * HW;
#pragma unroll
    for (int k = 0; k < 4; ++k) {
        const int iy = oy + row0 + 8 * k;
        o0[(size_t)iy * HW + ix] = acc0[k];
        o0[(size_t)HW * HW + (size_t)iy * HW + ix] = acc1[k];
    }
}

extern "C" void kernel_launch(void* const* d_in, const int* in_sizes, int n_in,
                              void* d_out, int out_size, void* d_ws, size_t ws_size,
                              hipStream_t stream) {
    const float* loc   = (const float*)d_in[0];
    const float* alpha = (const float*)d_in[1];
    float* ws_r    = (float*)d_ws;
    int*   ws_rm   = (int*)((char*)d_ws + 16);
    int*   counts  = (int*)((char*)d_ws + 64);
    int*   entries = (int*)((char*)d_ws + 8192);
    float* out = (float*)d_out;

    // Zero the per-tile counts (ws is poisoned 0xAA before every launch).
    hipMemsetAsync(counts, 0, sizeof(int) * BATCHN * NTILE, stream);

    maxmin_kernel<<<BATCHN, NPT, 0, stream>>>(loc, ws_r);
    finalize_kernel<<<1, 1, 0, stream>>>(ws_r, ws_rm);
    bin_kernel<<<BATCHN, NPT, 0, stream>>>(loc, ws_rm, counts, entries);
    // Gather covers every output pixel -> no d_out memset needed.
    gather_kernel<<<dim3(NTILE, BATCHN), 256, 0, stream>>>(loc, alpha, ws_r, ws_rm,
                                                           counts, entries, out);
}

// Round 6
// 117.994 us; speedup vs baseline: 1.3497x; 1.3497x over previous
//
#include <hip/hip_runtime.h>
#include <math.h>

#define HW       512
#define NPT      512
#define BATCHN   4
#define RMAX_CAP 37
#define CFACTOR  2.0f
#define TILE     32
#define TPD      (HW / TILE)      // 16
#define NTILE    (TPD * TPD)      // 256 tiles per batch (32x32 px)
#define CAP      512

// ws layout:
//   off 0    : float r[BATCHN]
//   off 64   : int   counts[BATCHN*NTILE]        (4 KiB)
//   off 8192 : int   entries[BATCHN*NTILE*CAP]   (2 MiB)

// One block per batch: (a) max-of-min NN distance -> r[b]; (b) bin all points
// into 32x32 tiles via LDS atomics (conservative box with rm=RMAX_CAP, a
// provable superset of actual coverage for any rm<=37). No global atomics,
// no memset needed.
__global__ __launch_bounds__(NPT) void prep_kernel(const float* __restrict__ loc,
                                                   float* __restrict__ ws_r,
                                                   int* __restrict__ counts,
                                                   int* __restrict__ entries) {
    __shared__ float2 pts[NPT];
    __shared__ float red[NPT / 64];
    __shared__ int lcnt[NTILE];
    const int b = blockIdx.x;
    const int t = threadIdx.x;
    const float2* L = (const float2*)(loc + (size_t)b * NPT * 2);
    pts[t] = L[t];
    if (t < NTILE) lcnt[t] = 0;
    __syncthreads();

    const float2 p = pts[t];
    float mind = 1e30f;
#pragma unroll 4
    for (int j = 0; j < NPT; ++j) {
        float dx = p.x - pts[j].x;
        float dy = p.y - pts[j].y;
        float d2 = dx * dx + dy * dy;
        if (j != t) mind = fminf(mind, d2);
    }
    float m = mind;
#pragma unroll
    for (int off = 1; off < 64; off <<= 1)
        m = fmaxf(m, __shfl_xor(m, off, 64));
    if ((t & 63) == 0) red[t >> 6] = m;

    // bin with cap-37 box (superset of any actual-rm coverage incl. +-1 slop)
    const float lo = (float)RMAX_CAP, hi = (float)(HW - RMAX_CAP);
    const float tx = fminf(fmaxf(p.x, lo), hi);
    const float ty = fminf(fmaxf(p.y, lo), hi);
    const int itx = (int)floorf(tx), ity = (int)floorf(ty);
    const int x0 = max(itx - RMAX_CAP - 1, 0), x1 = min(itx + RMAX_CAP + 1, HW - 1);
    const int y0 = max(ity - RMAX_CAP - 1, 0), y1 = min(ity + RMAX_CAP + 1, HW - 1);
    const int tx0 = x0 >> 5, tx1 = x1 >> 5;
    const int ty0 = y0 >> 5, ty1 = y1 >> 5;
    int* eb = entries + (size_t)b * NTILE * CAP;
    for (int tyi = ty0; tyi <= ty1; ++tyi)
        for (int txi = tx0; txi <= tx1; ++txi) {
            const int tile = tyi * TPD + txi;
            const int slot = atomicAdd(&lcnt[tile], 1);
            eb[tile * CAP + slot] = t;
        }
    __syncthreads();

    if (t < NTILE) counts[b * NTILE + t] = lcnt[t];
    if (t == 0) {
        float mm = red[0];
#pragma unroll
        for (int w = 1; w < NPT / 64; ++w) mm = fmaxf(mm, red[w]);
        ws_r[b] = sqrtf(mm) * CFACTOR;   // r[b] = maxmin NN dist * C_FACTOR
    }
}

// One block per (tile, strip, batch): a 32x8 pixel strip, 1 px/thread,
// scalar register accumulators, coalesced 128B-row stores.
// Faithful floor-anomaly multiplicity: per-point "safe" flag
// (frac == 0 exactly -> integer sums are exact in fp32, or frac in
// (1e-3, 1-1e-3): fp32 floor(c+t) == c+floor(t) guaranteed since rounding
// error <= ulp(549)/2 ~ 3e-5). Safe -> 1-compare unsigned-range window test,
// multiplicity 1; unsafe (rare) -> exact 3-candidate fp32-floor test
// (exhaustive: error < 1 so floor deviates by at most +-1).
__global__ __launch_bounds__(256) void gather_kernel(const float* __restrict__ loc,
                                                     const float* __restrict__ alpha,
                                                     const float* __restrict__ ws_r,
                                                     const int* __restrict__ counts,
                                                     const int* __restrict__ entries,
                                                     float* __restrict__ out) {
    __shared__ float s_x[CAP], s_y[CAP], s_tx[CAP], s_ty[CAP];
    __shared__ float s_a0[CAP], s_a1[CAP];
    __shared__ int s_itx[CAP], s_ity[CAP], s_safe[CAP];

    const int tile = blockIdx.x;          // 0..255
    const int strip = blockIdx.y;         // 0..3 (8-row strip within tile)
    const int b = blockIdx.z;
    const float rmaxf = fmaxf(fmaxf(ws_r[0], ws_r[1]), fmaxf(ws_r[2], ws_r[3]));
    const int rm = (int)fminf(ceilf(rmaxf), (float)RMAX_CAP);
    const float r = ws_r[b];
    const float inv_r = 1.0f / r;
    const float r2 = r * r;
    const float lo = (float)rm, hi = (float)(HW - rm);
    const int ox = (tile & (TPD - 1)) * TILE;
    const int oy = (tile >> 4) * TILE + strip * 8;
    const int count = counts[b * NTILE + tile];
    const int* ent = entries + (size_t)(b * NTILE + tile) * CAP;
    const float2* Lp = (const float2*)(loc + (size_t)b * NPT * 2);
    const float2* Ap = (const float2*)(alpha + (size_t)b * NPT * 2);

    // stage the tile's point list (count <= 512; <=2 passes of 256 threads)
    for (int j = threadIdx.x; j < count; j += 256) {
        const int n = ent[j];
        const float2 P = Lp[n];
        const float2 A = Ap[n];
        const float tx = fminf(fmaxf(P.x, lo), hi);
        const float ty = fminf(fmaxf(P.y, lo), hi);
        const float ftx = floorf(tx), fty = floorf(ty);
        s_x[j] = P.x; s_y[j] = P.y;
        s_tx[j] = tx; s_ty[j] = ty;
        s_itx[j] = (int)ftx; s_ity[j] = (int)fty;
        const float fx = tx - ftx, fy = ty - fty;
        const int sx_ok = (fx == 0.0f) || (fx > 1e-3f && fx < 1.0f - 1e-3f);
        const int sy_ok = (fy == 0.0f) || (fy > 1e-3f && fy < 1.0f - 1e-3f);
        s_safe[j] = sx_ok & sy_ok;
        s_a0[j] = A.x;
        s_a1[j] = A.y;
    }
    __syncthreads();

    const int ix = ox + (threadIdx.x & 31);
    const int iy = oy + (threadIdx.x >> 5);
    const float fix = (float)ix;
    const float fiy = (float)iy;
    float acc0 = 0.f, acc1 = 0.f;

    for (int j = 0; j < count; ++j) {
        const int safe = s_safe[j];
        const int bx = ix - s_itx[j];
        const int by = iy - s_ity[j];
        int mx, my;
        if (safe) {
            mx = ((unsigned)(bx + rm) < (unsigned)(2 * rm)) ? 1 : 0;
            my = ((unsigned)(by + rm) < (unsigned)(2 * rm)) ? 1 : 0;
        } else {
            const float tx = s_tx[j];
            const float ty = s_ty[j];
            mx = 0; my = 0;
#pragma unroll
            for (int d = -1; d <= 1; ++d) {
                const int cx = bx + d;
                if (cx >= -rm && cx < rm && floorf((float)cx + tx) == fix) ++mx;
                const int cy = by + d;
                if (cy >= -rm && cy < rm && floorf((float)cy + ty) == fiy) ++my;
            }
        }
        if ((mx & my) == 0 && (mx * my) == 0) continue;   // mx==0 || my==0

        const float ddx = fix - s_x[j];
        const float ddy = fiy - s_y[j];
        const float d2 = fmaf(ddy, ddy, ddx * ddx);
        if (d2 < r2) {                 // == (dist<1) up to quartic-zero boundary
            const float dist = sqrtf(d2) * inv_r;
            const float t1 = 1.0f - dist;
            const float t2 = t1 * t1;
            const float w = t2 * t2 * fmaf(4.0f, dist, 1.0f) * (float)(mx * my);
            acc0 = fmaf(w, s_a0[j], acc0);
            acc1 = fmaf(w, s_a1[j], acc1);
        }
    }

    float* o0 = out + (size_t)b * 2 * HW * HW + (size_t)iy * HW + ix;
    o0[0] = acc0;
    o0[HW * HW] = acc1;
}

extern "C" void kernel_launch(void* const* d_in, const int* in_sizes, int n_in,
                              void* d_out, int out_size, void* d_ws, size_t ws_size,
                              hipStream_t stream) {
    const float* loc   = (const float*)d_in[0];
    const float* alpha = (const float*)d_in[1];
    float* ws_r    = (float*)d_ws;
    int*   counts  = (int*)((char*)d_ws + 64);
    int*   entries = (int*)((char*)d_ws + 8192);
    float* out = (float*)d_out;

    prep_kernel<<<BATCHN, NPT, 0, stream>>>(loc, ws_r, counts, entries);
    gather_kernel<<<dim3(NTILE, 4, BATCHN), 256, 0, stream>>>(loc, alpha, ws_r,
                                                              counts, entries, out);
}

// Round 8
// 115.187 us; speedup vs baseline: 1.3826x; 1.0244x over previous
//
#include <hip/hip_runtime.h>
#include <math.h>

#define HW       512
#define NPT      512
#define BATCHN   4
#define RMAX_CAP 37
#define CFACTOR  2.0f
#define TILE     32
#define TPD      (HW / TILE)      // 16
#define NTILE    (TPD * TPD)      // 256 tiles per batch (32x32 px)
#define CAP      512

// ws layout:
//   off 0    : float r[BATCHN]
//   off 64   : int   counts[BATCHN*NTILE]        (4 KiB)
//   off 8192 : int   entries[BATCHN*NTILE*CAP]   (2 MiB)

// One block per batch: (a) max-of-min NN distance -> r[b]; (b) bin all points
// into 32x32 tiles via LDS atomics (conservative box with rm=RMAX_CAP, a
// provable superset of actual coverage for any rm<=37). No global atomics,
// no memset needed.
__global__ __launch_bounds__(NPT) void prep_kernel(const float* __restrict__ loc,
                                                   float* __restrict__ ws_r,
                                                   int* __restrict__ counts,
                                                   int* __restrict__ entries) {
    __shared__ float2 pts[NPT];
    __shared__ float red[NPT / 64];
    __shared__ int lcnt[NTILE];
    const int b = blockIdx.x;
    const int t = threadIdx.x;
    const float2* L = (const float2*)(loc + (size_t)b * NPT * 2);
    pts[t] = L[t];
    if (t < NTILE) lcnt[t] = 0;
    __syncthreads();

    const float2 p = pts[t];
    float mind = 1e30f;
#pragma unroll 4
    for (int j = 0; j < NPT; ++j) {
        float dx = p.x - pts[j].x;
        float dy = p.y - pts[j].y;
        float d2 = dx * dx + dy * dy;
        if (j != t) mind = fminf(mind, d2);
    }
    float m = mind;
#pragma unroll
    for (int off = 1; off < 64; off <<= 1)
        m = fmaxf(m, __shfl_xor(m, off, 64));
    if ((t & 63) == 0) red[t >> 6] = m;

    // bin with cap-37 box (superset of any actual-rm coverage incl. +-1 slop)
    const float lo = (float)RMAX_CAP, hi = (float)(HW - RMAX_CAP);
    const float tx = fminf(fmaxf(p.x, lo), hi);
    const float ty = fminf(fmaxf(p.y, lo), hi);
    const int itx = (int)floorf(tx), ity = (int)floorf(ty);
    const int x0 = max(itx - RMAX_CAP - 1, 0), x1 = min(itx + RMAX_CAP + 1, HW - 1);
    const int y0 = max(ity - RMAX_CAP - 1, 0), y1 = min(ity + RMAX_CAP + 1, HW - 1);
    const int tx0 = x0 >> 5, tx1 = x1 >> 5;
    const int ty0 = y0 >> 5, ty1 = y1 >> 5;
    int* eb = entries + (size_t)b * NTILE * CAP;
    for (int tyi = ty0; tyi <= ty1; ++tyi)
        for (int txi = tx0; txi <= tx1; ++txi) {
            const int tile = tyi * TPD + txi;
            const int slot = atomicAdd(&lcnt[tile], 1);
            eb[tile * CAP + slot] = t;
        }
    __syncthreads();

    if (t < NTILE) counts[b * NTILE + t] = lcnt[t];
    if (t == 0) {
        float mm = red[0];
#pragma unroll
        for (int w = 1; w < NPT / 64; ++w) mm = fmaxf(mm, red[w]);
        ws_r[b] = sqrtf(mm) * CFACTOR;   // r[b] = maxmin NN dist * C_FACTOR
    }
}

// One block per (tile, strip, batch): a 32x8 pixel strip, 1 px/thread, scalar
// register accumulators, coalesced 128B-row stores. Per-point LDS state packed
// into two b128 words: s_pt{x,y,a0,a1}, s_meta{itx,ity,safe,pad}; tx/ty
// (s_txy) read only on the rare unsafe path.
// Faithful floor-anomaly multiplicity: "safe" (frac == 0 exactly -> integer
// sums exact in fp32, or frac in (1e-3, 1-1e-3): fp32 floor(c+t) == c+floor(t)
// since rounding error <= ulp(549)/2 ~ 3e-5) -> 1-compare window test, mult 1;
// unsafe -> exact 3-candidate fp32-floor test (exhaustive: |err| < 1 so floor
// deviates by at most +-1).
__global__ __launch_bounds__(256) void gather_kernel(const float* __restrict__ loc,
                                                     const float* __restrict__ alpha,
                                                     const float* __restrict__ ws_r,
                                                     const int* __restrict__ counts,
                                                     const int* __restrict__ entries,
                                                     float* __restrict__ out) {
    __shared__ float4 s_pt[CAP];     // x, y, a0, a1
    __shared__ int4   s_meta[CAP];   // itx, ity, safe, pad
    __shared__ float2 s_txy[CAP];    // tx, ty (unsafe path only)

    const int tile = blockIdx.x;          // 0..255
    const int strip = blockIdx.y;         // 0..3 (8-row strip within tile)
    const int b = blockIdx.z;
    const float rmaxf = fmaxf(fmaxf(ws_r[0], ws_r[1]), fmaxf(ws_r[2], ws_r[3]));
    const int rm = (int)fminf(ceilf(rmaxf), (float)RMAX_CAP);
    const unsigned rm2u = (unsigned)(2 * rm);
    const float r = ws_r[b];
    const float inv_r = 1.0f / r;
    const float r2 = r * r;
    const float lo = (float)rm, hi = (float)(HW - rm);
    const int ox = (tile & (TPD - 1)) * TILE;
    const int oy = (tile >> 4) * TILE + strip * 8;
    const int count = counts[b * NTILE + tile];
    const int* ent = entries + (size_t)(b * NTILE + tile) * CAP;
    const float2* Lp = (const float2*)(loc + (size_t)b * NPT * 2);
    const float2* Ap = (const float2*)(alpha + (size_t)b * NPT * 2);

    // stage the tile's point list (count <= 512; <=2 passes of 256 threads)
    for (int j = threadIdx.x; j < count; j += 256) {
        const int n = ent[j];
        const float2 P = Lp[n];
        const float2 A = Ap[n];
        const float tx = fminf(fmaxf(P.x, lo), hi);
        const float ty = fminf(fmaxf(P.y, lo), hi);
        const float ftx = floorf(tx), fty = floorf(ty);
        const float fx = tx - ftx, fy = ty - fty;
        const int sx_ok = (fx == 0.0f) || (fx > 1e-3f && fx < 1.0f - 1e-3f);
        const int sy_ok = (fy == 0.0f) || (fy > 1e-3f && fy < 1.0f - 1e-3f);
        s_pt[j] = make_float4(P.x, P.y, A.x, A.y);
        s_meta[j] = make_int4((int)ftx, (int)fty, sx_ok & sy_ok, 0);
        s_txy[j] = make_float2(tx, ty);
    }
    __syncthreads();

    const int ix = ox + (threadIdx.x & 31);
    const int iy = oy + (threadIdx.x >> 5);
    const float fix = (float)ix;
    const float fiy = (float)iy;
    float acc0 = 0.f, acc1 = 0.f;

    for (int j = 0; j < count; ++j) {
        const int4 meta = s_meta[j];
        const int bx = ix - meta.x;
        const int by = iy - meta.y;
        int m;
        if (meta.z) {   // safe: multiplicity 1, pure range test (uniform branch)
            m = ((unsigned)(bx + rm) < rm2u) & ((unsigned)(by + rm) < rm2u);
        } else {        // unsafe: exact fp32-floor candidate count
            const float2 txy = s_txy[j];
            int mx = 0, my = 0;
#pragma unroll
            for (int d = -1; d <= 1; ++d) {
                const int cx = bx + d;
                if (cx >= -rm && cx < rm && floorf((float)cx + txy.x) == fix) ++mx;
                const int cy = by + d;
                if (cy >= -rm && cy < rm && floorf((float)cy + txy.y) == fiy) ++my;
            }
            m = mx * my;
        }
        if (m == 0) continue;

        const float4 pt = s_pt[j];
        const float ddx = fix - pt.x;
        const float ddy = fiy - pt.y;
        const float d2 = fmaf(ddx, ddx, ddy * ddy);
        if (d2 < r2) {                 // == (dist<1) up to quartic-zero boundary
            const float dist = sqrtf(d2) * inv_r;
            const float t1 = 1.0f - dist;
            const float t2 = t1 * t1;
            const float w = t2 * t2 * fmaf(4.0f, dist, 1.0f) * (float)m;
            acc0 = fmaf(w, pt.z, acc0);
            acc1 = fmaf(w, pt.w, acc1);
        }
    }

    float* o0 = out + (size_t)b * 2 * HW * HW + (size_t)iy * HW + ix;
    o0[0] = acc0;
    o0[HW * HW] = acc1;
}

extern "C" void kernel_launch(void* const* d_in, const int* in_sizes, int n_in,
                              void* d_out, int out_size, void* d_ws, size_t ws_size,
                              hipStream_t stream) {
    const float* loc   = (const float*)d_in[0];
    const float* alpha = (const float*)d_in[1];
    float* ws_r    = (float*)d_ws;
    int*   counts  = (int*)((char*)d_ws + 64);
    int*   entries = (int*)((char*)d_ws + 8192);
    float* out = (float*)d_out;

    prep_kernel<<<BATCHN, NPT, 0, stream>>>(loc, ws_r, counts, entries);
    gather_kernel<<<dim3(NTILE, 4, BATCHN), 256, 0, stream>>>(loc, alpha, ws_r,
                                                              counts, entries, out);
}